// Round 12
// baseline (341.220 us; speedup 1.0000x reference)
//
#include <hip/hip_runtime.h>

#define Bb_ 4
#define Hh_ 16
#define Ss_ 1024
#define DH 64
#define MAXLEN 2048
#define BH (Bb_*Hh_)
#define LDST 72   // 64 + 8 pad (bf16 elems)

typedef __attribute__((ext_vector_type(8))) short short8;
typedef __attribute__((ext_vector_type(4))) float floatx4;
typedef __attribute__((ext_vector_type(4))) unsigned short ushort4v;

static __device__ __forceinline__ unsigned short f2bf(float f) {
    unsigned int u = __builtin_bit_cast(unsigned int, f);
    u = (u + 0x7fffu + ((u >> 16) & 1u)) >> 16;   // RNE
    return (unsigned short)u;
}

// Stage a 128x64 fp32 tile -> bf16 LDS (row stride LDST)
static __device__ __forceinline__ void stage_tile128(unsigned short* lds,
                                                     const float* __restrict__ g,
                                                     int tid) {
#pragma unroll
    for (int it = 0; it < 8; ++it) {
        int idx = it * 1024 + tid * 4;
        int row = idx >> 6, col = idx & 63;
        const float4 v = *reinterpret_cast<const float4*>(g + row * 64 + col);
        ushort4v o = { f2bf(v.x), f2bf(v.y), f2bf(v.z), f2bf(v.w) };
        *reinterpret_cast<ushort4v*>(lds + row * LDST + col) = o;
    }
}

// Stage a 64x64 fp32 tile -> bf16 LDS (row stride LDST)
static __device__ __forceinline__ void stage_tile64(unsigned short* lds,
                                                    const float* __restrict__ g,
                                                    int tid) {
#pragma unroll
    for (int it = 0; it < 4; ++it) {
        int idx = it * 1024 + tid * 4;
        int row = idx >> 6, col = idx & 63;
        const float4 v = *reinterpret_cast<const float4*>(g + row * 64 + col);
        ushort4v o = { f2bf(v.x), f2bf(v.y), f2bf(v.z), f2bf(v.w) };
        *reinterpret_cast<ushort4v*>(lds + row * LDST + col) = o;
    }
}

// Fused CoPE, 64-col strips: block (bh, nt) computes ctx for its 64 t-rows,
// then emits the 1024 x 64 output column-strip. 1024 blocks, 3 blocks/CU.
// LDS: Aq [0,9216) | Kb0 [9216,27648) | Kb1 [27648,46080)
// Slow path reuses: AT = Kb0 region (128xLDST), Pb = Kb1 region (64xLDST).
__global__ __launch_bounds__(256, 3)
void cope_kernel(const float* __restrict__ q, const float* __restrict__ k,
                 const float* __restrict__ tb, float* __restrict__ out) {
    __shared__ __align__(16) unsigned char smem[46080];
    __shared__ float sh_ctx[64];
    __shared__ float sc[1024];
    __shared__ float2 sh_mm;

    unsigned short* Aq  = reinterpret_cast<unsigned short*>(smem);
    unsigned short* Kb0 = reinterpret_cast<unsigned short*>(smem + 9216);
    unsigned short* Kb1 = reinterpret_cast<unsigned short*>(smem + 27648);
    float* pr = reinterpret_cast<float*>(smem);  // fast path: Aq region dead

    int bx = blockIdx.x;
    // swizzle: the 16 blocks sharing this bh's k/q are 64 apart -> same XCD
    int bh = bx & 63, nt = bx >> 6;      // nt in [0,16)
    int n0 = nt << 6;
    int tid = threadIdx.x;
    int lane = tid & 63, w = tid >> 6;
    int lo = lane & 15, quad = lane >> 4;
    int rot = bx & 7;                    // k-tile start rotation

    const float* kb = k + (size_t)bh * Ss_ * DH;
    const float* qb = q + (size_t)bh * Ss_ * DH;

    // ---------------- Phase 1: ctx for rows n0..n0+63 ----------------
    stage_tile64(Aq, qb + (size_t)n0 * DH, tid);
    stage_tile128(Kb0, kb + (size_t)(rot << 7) * DH, tid);
    __syncthreads();

    short8 afr[2];   // wave w handles q-rows w*16 .. w*16+15
#pragma unroll
    for (int k2 = 0; k2 < 2; ++k2)
        afr[k2] = *reinterpret_cast<const short8*>(
            &Aq[(w * 16 + lo) * LDST + k2 * 32 + quad * 8]);

    float rp[4] = {0.f, 0.f, 0.f, 0.f};
    const float kSig = -0.18033688011112042f;  // -(1/8)*log2(e)

#pragma unroll 1
    for (int s = 0; s < 8; ++s) {
        const unsigned short* cur = (s & 1) ? Kb1 : Kb0;
        if (s < 7)
            stage_tile128((s & 1) ? Kb0 : Kb1,
                          kb + (size_t)(((rot + s + 1) & 7) << 7) * DH, tid);

        int t0 = ((rot + s) & 7) << 7;
#pragma unroll
        for (int j = 0; j < 8; ++j) {
            short8 b0 = *reinterpret_cast<const short8*>(
                &cur[(j * 16 + lo) * LDST + 0 + quad * 8]);
            short8 b1 = *reinterpret_cast<const short8*>(
                &cur[(j * 16 + lo) * LDST + 32 + quad * 8]);
            float tcol = (float)(t0 + j * 16 + lo);
            floatx4 c = {0.f, 0.f, 0.f, 0.f};
            c = __builtin_amdgcn_mfma_f32_16x16x32_bf16(afr[0], b0, c, 0, 0, 0);
            c = __builtin_amdgcn_mfma_f32_16x16x32_bf16(afr[1], b1, c, 0, 0, 0);
#pragma unroll
            for (int r = 0; r < 4; ++r) {
                float e = __builtin_amdgcn_exp2f(c[r] * kSig);
                float g = __builtin_amdgcn_rcpf(1.0f + e);
                rp[r] = fmaf(g, tcol, rp[r]);
            }
        }
        __syncthreads();
    }

    // reduce across the 16 lanes (score cols) sharing each row
#pragma unroll
    for (int r = 0; r < 4; ++r) {
        float v = rp[r];
        v += __shfl_xor(v, 1);
        v += __shfl_xor(v, 2);
        v += __shfl_xor(v, 4);
        v += __shfl_xor(v, 8);
        rp[r] = v;
    }

    if (lo == 0) {
#pragma unroll
        for (int r = 0; r < 4; ++r) {
            int lr = w * 16 + quad * 4 + r;
            sh_ctx[lr] = fminf(fmaxf(rp[r], 0.f), (float)(MAXLEN - 2));
        }
    }
    __syncthreads();

    if (tid < 64) {
        float mn = sh_ctx[tid], mx = mn;
#pragma unroll
        for (int off = 1; off < 64; off <<= 1) {
            mn = fminf(mn, __shfl_xor(mn, off));
            mx = fmaxf(mx, __shfl_xor(mx, off));
        }
        if (tid == 0) sh_mm = make_float2(mn, mx);
    }
    __syncthreads();

    float2 mmv = sh_mm;

    if (mmv.x == mmv.y) {
        // ---- FAST PATH: uniform ctx -> row-constant strip ----
        float v = mmv.x;
        int fl = (int)v;
        float fr = v - (float)fl;
        int ce = min(fl + 1, MAXLEN - 1);
        if (tid < 16) {
            int d0 = tid * 4;
            const float4 e0 = *reinterpret_cast<const float4*>(tb + fl * DH + d0);
            const float4 e1 = *reinterpret_cast<const float4*>(tb + ce * DH + d0);
            pr[d0 + 0] = e0.x + fr * (e1.x - e0.x);
            pr[d0 + 1] = e0.y + fr * (e1.y - e0.y);
            pr[d0 + 2] = e0.z + fr * (e1.z - e0.z);
            pr[d0 + 3] = e0.w + fr * (e1.w - e0.w);
        }
        __syncthreads();

        float ph[64];
#pragma unroll
        for (int d = 0; d < 64; ++d) ph[d] = pr[d];

        // All 1024 row dots up front (1 row per thread per pass)
#pragma unroll
        for (int it = 0; it < 4; ++it) {
            int row = it * 256 + tid;
            const float* qr = qb + (size_t)row * DH;
            float s0 = 0.f, s1 = 0.f, s2 = 0.f, s3 = 0.f;
#pragma unroll
            for (int d = 0; d < 64; d += 4) {
                const float4 qq = *reinterpret_cast<const float4*>(qr + d);
                s0 = fmaf(qq.x, ph[d + 0], s0);
                s1 = fmaf(qq.y, ph[d + 1], s1);
                s2 = fmaf(qq.z, ph[d + 2], s2);
                s3 = fmaf(qq.w, ph[d + 3], s3);
            }
            sc[row] = (s0 + s1) + (s2 + s3);
        }
        __syncthreads();

        // Uninterrupted store stream: 64 NT dwordx4 per thread, no barriers
#pragma unroll 4
        for (int it = 0; it < 64; ++it) {
            int flat = it * 1024 + tid * 4;
            int lrow = flat >> 6, col = flat & 63;
            float c = sc[lrow];
            floatx4 vv = {c, c, c, c};
            __builtin_nontemporal_store(
                vv, reinterpret_cast<floatx4*>(
                        out + (size_t)(bh * Ss_ + lrow) * Ss_ + n0 + col));
        }
        return;
    }

    // ---- SLOW PATH: build Pb (64 t-rows), then 8 m-tiles of MFMA GEMM ----
    unsigned short* AT = Kb0;   // 128xLDST
    unsigned short* Pb = Kb1;   // 64xLDST

    {
        int rsub = tid >> 4;       // 0..15
        int d0 = (tid & 15) * 4;   // 0..60
#pragma unroll
        for (int pass = 0; pass < 4; ++pass) {
            int row = pass * 16 + rsub;
            float c = sh_ctx[row];
            int fl = (int)c;
            float fr = c - (float)fl;
            int ce = min(fl + 1, MAXLEN - 1);
            const float4 e0 = *reinterpret_cast<const float4*>(tb + fl * DH + d0);
            const float4 e1 = *reinterpret_cast<const float4*>(tb + ce * DH + d0);
            ushort4v o = { f2bf(e0.x + fr * (e1.x - e0.x)),
                           f2bf(e0.y + fr * (e1.y - e0.y)),
                           f2bf(e0.z + fr * (e1.z - e0.z)),
                           f2bf(e0.w + fr * (e1.w - e0.w)) };
            *reinterpret_cast<ushort4v*>(&Pb[row * LDST + d0]) = o;
        }
    }
    __syncthreads();

    short8 bfr[4][2];
#pragma unroll
    for (int j = 0; j < 4; ++j) {
        bfr[j][0] = *reinterpret_cast<const short8*>(
            &Pb[(j * 16 + lo) * LDST + 0 + quad * 8]);
        bfr[j][1] = *reinterpret_cast<const short8*>(
            &Pb[(j * 16 + lo) * LDST + 32 + quad * 8]);
    }

#pragma unroll 1
    for (int mt = 0; mt < 8; ++mt) {
        int m0 = mt << 7;
        stage_tile128(AT, qb + (size_t)m0 * DH, tid);
        __syncthreads();

        short8 mfr[2][2];
#pragma unroll
        for (int i = 0; i < 2; ++i)
#pragma unroll
            for (int k2 = 0; k2 < 2; ++k2)
                mfr[i][k2] = *reinterpret_cast<const short8*>(
                    &AT[(w * 32 + i * 16 + lo) * LDST + k2 * 32 + quad * 8]);

        floatx4 acc[2][4];
#pragma unroll
        for (int i = 0; i < 2; ++i)
#pragma unroll
            for (int j = 0; j < 4; ++j) acc[i][j] = (floatx4){0.f, 0.f, 0.f, 0.f};

#pragma unroll
        for (int j = 0; j < 4; ++j)
#pragma unroll
            for (int i = 0; i < 2; ++i) {
                acc[i][j] = __builtin_amdgcn_mfma_f32_16x16x32_bf16(
                    mfr[i][0], bfr[j][0], acc[i][j], 0, 0, 0);
                acc[i][j] = __builtin_amdgcn_mfma_f32_16x16x32_bf16(
                    mfr[i][1], bfr[j][1], acc[i][j], 0, 0, 0);
            }

        // cached scalar stores (proven neutral vs transposed epilogue)
#pragma unroll
        for (int i = 0; i < 2; ++i)
#pragma unroll
            for (int j = 0; j < 4; ++j)
#pragma unroll
                for (int r = 0; r < 4; ++r) {
                    int row = m0 + w * 32 + i * 16 + quad * 4 + r;
                    int col = n0 + j * 16 + lo;
                    out[(size_t)(bh * Ss_ + row) * Ss_ + col] = acc[i][j][r];
                }
        __syncthreads();  // AT safe to restage
    }
}

extern "C" void kernel_launch(void* const* d_in, const int* in_sizes, int n_in,
                              void* d_out, int out_size, void* d_ws, size_t ws_size,
                              hipStream_t stream) {
    const float* q  = (const float*)d_in[0];
    const float* k  = (const float*)d_in[1];
    const float* tb = (const float*)d_in[2];
    float* out = (float*)d_out;

    cope_kernel<<<BH * 16, 256, 0, stream>>>(q, k, tb, out);
}

// Round 13
// 323.439 us; speedup vs baseline: 1.0550x; 1.0550x over previous
//
#include <hip/hip_runtime.h>

#define Bb_ 4
#define Hh_ 16
#define Ss_ 1024
#define DH 64
#define MAXLEN 2048
#define BH (Bb_*Hh_)
#define LDST 72   // 64 + 8 pad (bf16 elems)
#define SW 132    // fp32 epilogue scratch stride (128 + 4 pad words)

typedef __attribute__((ext_vector_type(8))) short short8;
typedef __attribute__((ext_vector_type(4))) float floatx4;
typedef __attribute__((ext_vector_type(4))) unsigned short ushort4v;

static __device__ __forceinline__ unsigned short f2bf(float f) {
    unsigned int u = __builtin_bit_cast(unsigned int, f);
    u = (u + 0x7fffu + ((u >> 16) & 1u)) >> 16;   // RNE
    return (unsigned short)u;
}

// Stage a 128x64 fp32 tile (row stride 64) -> bf16 LDS tile (row stride LDST)
static __device__ __forceinline__ void stage_tile(unsigned short* lds,
                                                  const float* __restrict__ g,
                                                  int tid) {
#pragma unroll
    for (int it = 0; it < 8; ++it) {
        int idx = it * 1024 + tid * 4;
        int row = idx >> 6, col = idx & 63;
        const float4 v = *reinterpret_cast<const float4*>(g + row * 64 + col);
        ushort4v o = { f2bf(v.x), f2bf(v.y), f2bf(v.z), f2bf(v.w) };
        *reinterpret_cast<ushort4v*>(lds + row * LDST + col) = o;
    }
}

// Fused CoPE (R11 structure): block (bh, nt) computes ctx for its 128 t-rows
// (phase 1), then emits the full 1024 x 128 output column-strip (phase 3).
// R13 delta: fast path computes ALL 1024 row-dots first, then one
// uninterrupted NT store stream (no per-m-tile barriers).
__global__ __launch_bounds__(256, 2)
void cope_kernel(const float* __restrict__ q, const float* __restrict__ k,
                 const float* __restrict__ tb, float* __restrict__ out) {
    __shared__ __align__(16) unsigned char smem[73728];
    __shared__ float sh_ctx[128];
    __shared__ float sc[1024];
    __shared__ float2 sh_mm;

    unsigned short* Ab = reinterpret_cast<unsigned short*>(smem);
    unsigned short* Kb0 = reinterpret_cast<unsigned short*>(smem + 18432);
    unsigned short* Kb1 = reinterpret_cast<unsigned short*>(smem + 36864);
    float* scratch = reinterpret_cast<float*>(smem + 18432);
    unsigned short* Pb = reinterpret_cast<unsigned short*>(smem + 55296);
    float* pr = reinterpret_cast<float*>(smem);  // fast path: Ab region dead

    int bx = blockIdx.x;
    // swizzle: blocks sharing this bh's k-stream are 64 apart -> same XCD
    int bh = bx & 63, nt = bx >> 6;
    int n0 = nt << 7;
    int tid = threadIdx.x;
    int lane = tid & 63, w = tid >> 6;
    int lo = lane & 15, quad = lane >> 4;

    const float* kb = k + (size_t)bh * Ss_ * DH;
    const float* qb = q + (size_t)bh * Ss_ * DH;

    // ---------------- Phase 1: ctx for rows n0..n0+127 ----------------
    stage_tile(Ab, qb + (size_t)n0 * DH, tid);
    stage_tile(Kb0, kb, tid);
    __syncthreads();

    short8 afr[2][2];
#pragma unroll
    for (int i = 0; i < 2; ++i)
#pragma unroll
        for (int k2 = 0; k2 < 2; ++k2)
            afr[i][k2] = *reinterpret_cast<const short8*>(
                &Ab[(w * 32 + i * 16 + lo) * LDST + k2 * 32 + quad * 8]);

    float rp[2][4];
#pragma unroll
    for (int i = 0; i < 2; ++i)
#pragma unroll
        for (int r = 0; r < 4; ++r) rp[i][r] = 0.f;

    const float kSig = -0.18033688011112042f;  // -(1/8)*log2(e)

#pragma unroll 1
    for (int tt = 0; tt < 8; ++tt) {
        const unsigned short* cur = (tt & 1) ? Kb1 : Kb0;
        if (tt < 7)
            stage_tile((tt & 1) ? Kb0 : Kb1, kb + (size_t)(tt + 1) * 128 * DH, tid);

        int t0 = tt << 7;
#pragma unroll
        for (int j = 0; j < 8; ++j) {
            short8 b0 = *reinterpret_cast<const short8*>(
                &cur[(j * 16 + lo) * LDST + 0 + quad * 8]);
            short8 b1 = *reinterpret_cast<const short8*>(
                &cur[(j * 16 + lo) * LDST + 32 + quad * 8]);
            float tcol = (float)(t0 + j * 16 + lo);
#pragma unroll
            for (int i = 0; i < 2; ++i) {
                floatx4 c = {0.f, 0.f, 0.f, 0.f};
                c = __builtin_amdgcn_mfma_f32_16x16x32_bf16(afr[i][0], b0, c, 0, 0, 0);
                c = __builtin_amdgcn_mfma_f32_16x16x32_bf16(afr[i][1], b1, c, 0, 0, 0);
#pragma unroll
                for (int r = 0; r < 4; ++r) {
                    float e = __builtin_amdgcn_exp2f(c[r] * kSig);
                    float g = __builtin_amdgcn_rcpf(1.0f + e);
                    rp[i][r] = fmaf(g, tcol, rp[i][r]);
                }
            }
        }
        __syncthreads();
    }

#pragma unroll
    for (int i = 0; i < 2; ++i)
#pragma unroll
        for (int r = 0; r < 4; ++r) {
            float v = rp[i][r];
            v += __shfl_xor(v, 1);
            v += __shfl_xor(v, 2);
            v += __shfl_xor(v, 4);
            v += __shfl_xor(v, 8);
            rp[i][r] = v;
        }

    if (lo == 0) {
#pragma unroll
        for (int i = 0; i < 2; ++i)
#pragma unroll
            for (int r = 0; r < 4; ++r) {
                int lr = w * 32 + i * 16 + quad * 4 + r;
                sh_ctx[lr] = fminf(fmaxf(rp[i][r], 0.f), (float)(MAXLEN - 2));
            }
    }
    __syncthreads();

    // Local min/max over the 128 ctx values
    if (tid < 64) {
        float a = sh_ctx[tid], b = sh_ctx[tid + 64];
        float mn = fminf(a, b), mx = fmaxf(a, b);
#pragma unroll
        for (int off = 1; off < 64; off <<= 1) {
            mn = fminf(mn, __shfl_xor(mn, off));
            mx = fmaxf(mx, __shfl_xor(mx, off));
        }
        if (tid == 0) sh_mm = make_float2(mn, mx);
    }
    __syncthreads();

    float2 mmv = sh_mm;

    if (mmv.x == mmv.y) {
        // ------- FAST PATH: uniform ctx -> row-constant strip -------
        float v = mmv.x;
        int fl = (int)v;
        float fr = v - (float)fl;
        int ce = min(fl + 1, MAXLEN - 1);
        if (tid < 16) {
            int d0 = tid * 4;
            const float4 e0 = *reinterpret_cast<const float4*>(tb + fl * DH + d0);
            const float4 e1 = *reinterpret_cast<const float4*>(tb + ce * DH + d0);
            pr[d0 + 0] = e0.x + fr * (e1.x - e0.x);
            pr[d0 + 1] = e0.y + fr * (e1.y - e0.y);
            pr[d0 + 2] = e0.z + fr * (e1.z - e0.z);
            pr[d0 + 3] = e0.w + fr * (e1.w - e0.w);
        }
        __syncthreads();

        // register-cache half the emb row (R11 pattern: 2 threads per q-row)
        float ph[32];
        {
            int half = tid & 1;
#pragma unroll
            for (int d = 0; d < 32; ++d) ph[d] = pr[half * 32 + d];
        }

        // ALL 1024 row dots up front: 8 passes x 128 rows (2 threads/row)
#pragma unroll
        for (int pass = 0; pass < 8; ++pass) {
            int row = pass * 128 + (tid >> 1);
            int half = tid & 1;
            const float* qr = qb + (size_t)row * DH + half * 32;
            float s = 0.f;
#pragma unroll
            for (int d = 0; d < 32; d += 4) {
                const float4 qq = *reinterpret_cast<const float4*>(qr + d);
                s += qq.x * ph[d] + qq.y * ph[d + 1] + qq.z * ph[d + 2] +
                     qq.w * ph[d + 3];
            }
            s += __shfl_xor(s, 1);
            if (half == 0) sc[row] = s;
        }
        __syncthreads();

        // One uninterrupted NT store stream: 128 dwordx4 insts per thread.
        // Per wave-inst: 2 rows x 512 B contiguous (full L2 lines).
#pragma unroll 8
        for (int it = 0; it < 128; ++it) {
            int flat = it * 1024 + tid * 4;
            int lrow = flat >> 7, col = flat & 127;
            float c = sc[lrow];
            floatx4 vv = {c, c, c, c};
            __builtin_nontemporal_store(
                vv, reinterpret_cast<floatx4*>(
                        out + (size_t)(bh * Ss_ + lrow) * Ss_ + n0 + col));
        }
        return;
    }

    // ------- SLOW PATH: build Pb, then 8 m-tiles of MFMA GEMM -------
    {
        int rsub = tid >> 4;       // 0..15
        int d0 = (tid & 15) * 4;   // 0..60
#pragma unroll
        for (int pass = 0; pass < 8; ++pass) {
            int row = pass * 16 + rsub;
            float c = sh_ctx[row];
            int fl = (int)c;
            float fr = c - (float)fl;
            int ce = min(fl + 1, MAXLEN - 1);
            const float4 e0 = *reinterpret_cast<const float4*>(tb + fl * DH + d0);
            const float4 e1 = *reinterpret_cast<const float4*>(tb + ce * DH + d0);
            ushort4v o = { f2bf(e0.x + fr * (e1.x - e0.x)),
                           f2bf(e0.y + fr * (e1.y - e0.y)),
                           f2bf(e0.z + fr * (e1.z - e0.z)),
                           f2bf(e0.w + fr * (e1.w - e0.w)) };
            *reinterpret_cast<ushort4v*>(&Pb[row * LDST + d0]) = o;
        }
    }
    __syncthreads();

    // B-fragments are loop-invariant across m-tiles: hoist to registers
    short8 bfr[8][2];
#pragma unroll
    for (int j = 0; j < 8; ++j) {
        bfr[j][0] = *reinterpret_cast<const short8*>(
            &Pb[(j * 16 + lo) * LDST + 0 + quad * 8]);
        bfr[j][1] = *reinterpret_cast<const short8*>(
            &Pb[(j * 16 + lo) * LDST + 32 + quad * 8]);
    }

#pragma unroll 1
    for (int mt = 0; mt < 8; ++mt) {
        int m0 = mt << 7;
        stage_tile(Ab, qb + (size_t)m0 * DH, tid);
        __syncthreads();

        short8 mfr[2][2];
#pragma unroll
        for (int i = 0; i < 2; ++i)
#pragma unroll
            for (int k2 = 0; k2 < 2; ++k2)
                mfr[i][k2] = *reinterpret_cast<const short8*>(
                    &Ab[(w * 32 + i * 16 + lo) * LDST + k2 * 32 + quad * 8]);

        floatx4 acc[2][8];
#pragma unroll
        for (int i = 0; i < 2; ++i)
#pragma unroll
            for (int j = 0; j < 8; ++j) acc[i][j] = (floatx4){0.f, 0.f, 0.f, 0.f};

#pragma unroll
        for (int j = 0; j < 8; ++j)
#pragma unroll
            for (int i = 0; i < 2; ++i) {
                acc[i][j] = __builtin_amdgcn_mfma_f32_16x16x32_bf16(
                    mfr[i][0], bfr[j][0], acc[i][j], 0, 0, 0);
                acc[i][j] = __builtin_amdgcn_mfma_f32_16x16x32_bf16(
                    mfr[i][1], bfr[j][1], acc[i][j], 0, 0, 0);
            }

        // Epilogue: LDS transpose -> contiguous dwordx4 NT stores
#pragma unroll
        for (int i = 0; i < 2; ++i) {
            __syncthreads();
#pragma unroll
            for (int j = 0; j < 8; ++j)
#pragma unroll
                for (int r = 0; r < 4; ++r) {
                    int lrow = w * 16 + quad * 4 + r;
                    scratch[lrow * SW + j * 16 + lo] = acc[i][j][r];
                }
            __syncthreads();
#pragma unroll
            for (int it = 0; it < 8; ++it) {
                int flat = it * 1024 + tid * 4;
                int lrow = flat >> 7, col = flat & 127;
                floatx4 vv =
                    *reinterpret_cast<const floatx4*>(&scratch[lrow * SW + col]);
                int grow = m0 + (lrow >> 4) * 32 + i * 16 + (lrow & 15);
                __builtin_nontemporal_store(
                    vv, reinterpret_cast<floatx4*>(
                            out + (size_t)(bh * Ss_ + grow) * Ss_ + n0 + col));
            }
        }
        __syncthreads();  // scratch/Ab safe for next mt
    }
}

extern "C" void kernel_launch(void* const* d_in, const int* in_sizes, int n_in,
                              void* d_out, int out_size, void* d_ws, size_t ws_size,
                              hipStream_t stream) {
    const float* q  = (const float*)d_in[0];
    const float* k  = (const float*)d_in[1];
    const float* tb = (const float*)d_in[2];
    float* out = (float*)d_out;

    cope_kernel<<<BH * 8, 256, 0, stream>>>(q, k, tb, out);
}

// Round 14
// 308.707 us; speedup vs baseline: 1.1053x; 1.0477x over previous
//
#include <hip/hip_runtime.h>

#define Bb_ 4
#define Hh_ 16
#define Ss_ 1024
#define DH 64
#define MAXLEN 2048
#define BH (Bb_*Hh_)
#define LDST 72   // 64 + 8 pad (bf16 elems)
#define SW 132    // fp32 epilogue scratch stride (128 + 4 pad words)

typedef __attribute__((ext_vector_type(8))) short short8;
typedef __attribute__((ext_vector_type(4))) float floatx4;
typedef __attribute__((ext_vector_type(4))) unsigned short ushort4v;

static __device__ __forceinline__ unsigned short f2bf(float f) {
    unsigned int u = __builtin_bit_cast(unsigned int, f);
    u = (u + 0x7fffu + ((u >> 16) & 1u)) >> 16;   // RNE
    return (unsigned short)u;
}

// Stage a 128x64 fp32 tile (row stride 64) -> bf16 LDS tile (row stride LDST)
static __device__ __forceinline__ void stage_tile(unsigned short* lds,
                                                  const float* __restrict__ g,
                                                  int tid) {
#pragma unroll
    for (int it = 0; it < 8; ++it) {
        int idx = it * 1024 + tid * 4;
        int row = idx >> 6, col = idx & 63;
        const float4 v = *reinterpret_cast<const float4*>(g + row * 64 + col);
        ushort4v o = { f2bf(v.x), f2bf(v.y), f2bf(v.z), f2bf(v.w) };
        *reinterpret_cast<ushort4v*>(lds + row * LDST + col) = o;
    }
}

// Fused CoPE (R11 proven-best, 310.5 us): block (bh, nt) computes ctx for its
// 128 t-rows (phase 1), then emits the full 1024 x 128 output column-strip.
// Fast path interleaves dot-pass and store-burst per m-tile: stores start
// ~1/8 into phase 3 (convoy-friendly; R13's dots-up-front regressed).
__global__ __launch_bounds__(256, 2)
void cope_kernel(const float* __restrict__ q, const float* __restrict__ k,
                 const float* __restrict__ tb, float* __restrict__ out) {
    __shared__ __align__(16) unsigned char smem[73728];
    __shared__ float sh_ctx[128];
    __shared__ float sh_sc[128];
    __shared__ float2 sh_mm;

    unsigned short* Ab = reinterpret_cast<unsigned short*>(smem);
    unsigned short* Kb0 = reinterpret_cast<unsigned short*>(smem + 18432);
    unsigned short* Kb1 = reinterpret_cast<unsigned short*>(smem + 36864);
    float* scratch = reinterpret_cast<float*>(smem + 18432);
    unsigned short* Pb = reinterpret_cast<unsigned short*>(smem + 55296);
    float* pr = sh_sc;  // fast path: fp32 emb row cache (64 floats)

    int bx = blockIdx.x;
    // swizzle: blocks sharing this bh's k-stream are 64 apart -> same XCD
    int bh = bx & 63, nt = bx >> 6;
    int n0 = nt << 7;
    int tid = threadIdx.x;
    int lane = tid & 63, w = tid >> 6;
    int lo = lane & 15, quad = lane >> 4;

    const float* kb = k + (size_t)bh * Ss_ * DH;
    const float* qb = q + (size_t)bh * Ss_ * DH;

    // ---------------- Phase 1: ctx for rows n0..n0+127 ----------------
    stage_tile(Ab, qb + (size_t)n0 * DH, tid);
    stage_tile(Kb0, kb, tid);
    __syncthreads();

    short8 afr[2][2];
#pragma unroll
    for (int i = 0; i < 2; ++i)
#pragma unroll
        for (int k2 = 0; k2 < 2; ++k2)
            afr[i][k2] = *reinterpret_cast<const short8*>(
                &Ab[(w * 32 + i * 16 + lo) * LDST + k2 * 32 + quad * 8]);

    float rp[2][4];
#pragma unroll
    for (int i = 0; i < 2; ++i)
#pragma unroll
        for (int r = 0; r < 4; ++r) rp[i][r] = 0.f;

    const float kSig = -0.18033688011112042f;  // -(1/8)*log2(e)

#pragma unroll 1
    for (int tt = 0; tt < 8; ++tt) {
        const unsigned short* cur = (tt & 1) ? Kb1 : Kb0;
        if (tt < 7)
            stage_tile((tt & 1) ? Kb0 : Kb1, kb + (size_t)(tt + 1) * 128 * DH, tid);

        int t0 = tt << 7;
#pragma unroll
        for (int j = 0; j < 8; ++j) {
            short8 b0 = *reinterpret_cast<const short8*>(
                &cur[(j * 16 + lo) * LDST + 0 + quad * 8]);
            short8 b1 = *reinterpret_cast<const short8*>(
                &cur[(j * 16 + lo) * LDST + 32 + quad * 8]);
            float tcol = (float)(t0 + j * 16 + lo);
#pragma unroll
            for (int i = 0; i < 2; ++i) {
                floatx4 c = {0.f, 0.f, 0.f, 0.f};
                c = __builtin_amdgcn_mfma_f32_16x16x32_bf16(afr[i][0], b0, c, 0, 0, 0);
                c = __builtin_amdgcn_mfma_f32_16x16x32_bf16(afr[i][1], b1, c, 0, 0, 0);
#pragma unroll
                for (int r = 0; r < 4; ++r) {
                    float e = __builtin_amdgcn_exp2f(c[r] * kSig);
                    float g = __builtin_amdgcn_rcpf(1.0f + e);
                    rp[i][r] = fmaf(g, tcol, rp[i][r]);
                }
            }
        }
        __syncthreads();
    }

#pragma unroll
    for (int i = 0; i < 2; ++i)
#pragma unroll
        for (int r = 0; r < 4; ++r) {
            float v = rp[i][r];
            v += __shfl_xor(v, 1);
            v += __shfl_xor(v, 2);
            v += __shfl_xor(v, 4);
            v += __shfl_xor(v, 8);
            rp[i][r] = v;
        }

    if (lo == 0) {
#pragma unroll
        for (int i = 0; i < 2; ++i)
#pragma unroll
            for (int r = 0; r < 4; ++r) {
                int lr = w * 32 + i * 16 + quad * 4 + r;
                sh_ctx[lr] = fminf(fmaxf(rp[i][r], 0.f), (float)(MAXLEN - 2));
            }
    }
    __syncthreads();

    // Local min/max over the 128 ctx values
    if (tid < 64) {
        float a = sh_ctx[tid], b = sh_ctx[tid + 64];
        float mn = fminf(a, b), mx = fmaxf(a, b);
#pragma unroll
        for (int off = 1; off < 64; off <<= 1) {
            mn = fminf(mn, __shfl_xor(mn, off));
            mx = fmaxf(mx, __shfl_xor(mx, off));
        }
        if (tid == 0) sh_mm = make_float2(mn, mx);
    }
    __syncthreads();

    float2 mmv = sh_mm;

    if (mmv.x == mmv.y) {
        // ------- FAST PATH: all local ctx equal -> row-constant strip -------
        float v = mmv.x;
        int fl = (int)v;
        float fr = v - (float)fl;
        int ce = min(fl + 1, MAXLEN - 1);
        if (tid < 16) {
            int d0 = tid * 4;
            const float4 e0 = *reinterpret_cast<const float4*>(tb + fl * DH + d0);
            const float4 e1 = *reinterpret_cast<const float4*>(tb + ce * DH + d0);
            pr[d0 + 0] = e0.x + fr * (e1.x - e0.x);
            pr[d0 + 1] = e0.y + fr * (e1.y - e0.y);
            pr[d0 + 2] = e0.z + fr * (e1.z - e0.z);
            pr[d0 + 3] = e0.w + fr * (e1.w - e0.w);
        }
        __syncthreads();

        // cache emb half-row in registers (2 threads per q-row)
        float ph[32];
        {
            int half = tid & 1;
#pragma unroll
            for (int d = 0; d < 32; ++d) ph[d] = pr[half * 32 + d];
        }

#pragma unroll 1
        for (int mt = 0; mt < 8; ++mt) {
            int m0 = mt << 7;
            // fp32 dots: 2 threads per row (halves), 256 threads = 128 rows
            {
                int row = tid >> 1, half = tid & 1;
                const float* qr = qb + (size_t)(m0 + row) * DH + half * 32;
                float s = 0.f;
#pragma unroll
                for (int d = 0; d < 32; d += 4) {
                    const float4 qq = *reinterpret_cast<const float4*>(qr + d);
                    s += qq.x * ph[d] + qq.y * ph[d + 1] + qq.z * ph[d + 2] +
                         qq.w * ph[d + 3];
                }
                s += __shfl_xor(s, 1);
                if (half == 0) sh_ctx[row] = s;   // reuse sh_ctx as row consts
            }
            __syncthreads();

            // Stream 128x128: each wave-inst writes 1 KB of full lines
#pragma unroll
            for (int it = 0; it < 16; ++it) {
                int flat = (it * 256 + tid) * 4;
                int lrow = flat >> 7, col = flat & 127;
                float c = sh_ctx[lrow];
                floatx4 vv = {c, c, c, c};
                __builtin_nontemporal_store(
                    vv, reinterpret_cast<floatx4*>(
                            out + (size_t)(bh * Ss_ + m0 + lrow) * Ss_ + n0 + col));
            }
            __syncthreads();
        }
        return;
    }

    // ------- SLOW PATH: build Pb, then 8 m-tiles of MFMA GEMM -------
    {
        int rsub = tid >> 4;       // 0..15
        int d0 = (tid & 15) * 4;   // 0..60
#pragma unroll
        for (int pass = 0; pass < 8; ++pass) {
            int row = pass * 16 + rsub;
            float c = sh_ctx[row];
            int fl = (int)c;
            float fr = c - (float)fl;
            int ce = min(fl + 1, MAXLEN - 1);
            const float4 e0 = *reinterpret_cast<const float4*>(tb + fl * DH + d0);
            const float4 e1 = *reinterpret_cast<const float4*>(tb + ce * DH + d0);
            ushort4v o = { f2bf(e0.x + fr * (e1.x - e0.x)),
                           f2bf(e0.y + fr * (e1.y - e0.y)),
                           f2bf(e0.z + fr * (e1.z - e0.z)),
                           f2bf(e0.w + fr * (e1.w - e0.w)) };
            *reinterpret_cast<ushort4v*>(&Pb[row * LDST + d0]) = o;
        }
    }
    __syncthreads();

    // B-fragments are loop-invariant across m-tiles: hoist to registers
    short8 bfr[8][2];
#pragma unroll
    for (int j = 0; j < 8; ++j) {
        bfr[j][0] = *reinterpret_cast<const short8*>(
            &Pb[(j * 16 + lo) * LDST + 0 + quad * 8]);
        bfr[j][1] = *reinterpret_cast<const short8*>(
            &Pb[(j * 16 + lo) * LDST + 32 + quad * 8]);
    }

#pragma unroll 1
    for (int mt = 0; mt < 8; ++mt) {
        int m0 = mt << 7;
        stage_tile(Ab, qb + (size_t)m0 * DH, tid);
        __syncthreads();

        short8 mfr[2][2];
#pragma unroll
        for (int i = 0; i < 2; ++i)
#pragma unroll
            for (int k2 = 0; k2 < 2; ++k2)
                mfr[i][k2] = *reinterpret_cast<const short8*>(
                    &Ab[(w * 32 + i * 16 + lo) * LDST + k2 * 32 + quad * 8]);

        floatx4 acc[2][8];
#pragma unroll
        for (int i = 0; i < 2; ++i)
#pragma unroll
            for (int j = 0; j < 8; ++j) acc[i][j] = (floatx4){0.f, 0.f, 0.f, 0.f};

#pragma unroll
        for (int j = 0; j < 8; ++j)
#pragma unroll
            for (int i = 0; i < 2; ++i) {
                acc[i][j] = __builtin_amdgcn_mfma_f32_16x16x32_bf16(
                    mfr[i][0], bfr[j][0], acc[i][j], 0, 0, 0);
                acc[i][j] = __builtin_amdgcn_mfma_f32_16x16x32_bf16(
                    mfr[i][1], bfr[j][1], acc[i][j], 0, 0, 0);
            }

        // Epilogue: LDS transpose -> contiguous dwordx4 NT stores
#pragma unroll
        for (int i = 0; i < 2; ++i) {
            __syncthreads();
#pragma unroll
            for (int j = 0; j < 8; ++j)
#pragma unroll
                for (int r = 0; r < 4; ++r) {
                    int lrow = w * 16 + quad * 4 + r;
                    scratch[lrow * SW + j * 16 + lo] = acc[i][j][r];
                }
            __syncthreads();
#pragma unroll
            for (int it = 0; it < 8; ++it) {
                int flat = it * 1024 + tid * 4;
                int lrow = flat >> 7, col = flat & 127;
                floatx4 vv =
                    *reinterpret_cast<const floatx4*>(&scratch[lrow * SW + col]);
                int grow = m0 + (lrow >> 4) * 32 + i * 16 + (lrow & 15);
                __builtin_nontemporal_store(
                    vv, reinterpret_cast<floatx4*>(
                            out + (size_t)(bh * Ss_ + grow) * Ss_ + n0 + col));
            }
        }
        __syncthreads();  // scratch/Ab safe for next mt
    }
}

extern "C" void kernel_launch(void* const* d_in, const int* in_sizes, int n_in,
                              void* d_out, int out_size, void* d_ws, size_t ws_size,
                              hipStream_t stream) {
    const float* q  = (const float*)d_in[0];
    const float* k  = (const float*)d_in[1];
    const float* tb = (const float*)d_in[2];
    float* out = (float*)d_out;

    cope_kernel<<<BH * 8, 256, 0, stream>>>(q, k, tb, out);
}